// Round 8
// baseline (238.181 us; speedup 1.0000x reference)
//
#include <hip/hip_runtime.h>

// Problem constants
constexpr int Bb   = 2;
constexpr int Nn   = 2048;
constexpr int Hh   = 8;
constexpr int Dd   = 64;
constexpr int Mm   = Bb * Nn;      // 4096 rows
constexpr int TQKV = 1536;         // 3 * H * D
constexpr int INNER = Hh * Dd;     // 512
constexpr int CH   = 64;           // chunk length
constexpr int NCH  = Nn / CH;      // 32 chunks per (b,h)
constexpr int CSZ  = Dd * Dd + Dd; // 4160 floats per chunk record (S + kc)
constexpr float EPSF = 1e-7f;

typedef _Float16 half8 __attribute__((ext_vector_type(8)));
typedef _Float16 half4 __attribute__((ext_vector_type(4)));
typedef float f32x4 __attribute__((ext_vector_type(4)));

#define AS1(p) ((const __attribute__((address_space(1))) unsigned int*)(p))
#define AS3(p) ((__attribute__((address_space(3))) unsigned int*)(p))

// ---------------------------------------------------------------------------
// GEMM1 (fp32 VALU, pk-fma): qkv = x[4096,512] * w_qkv[1536,512]^T.
// R2-R6 verdict: q/k need fp32-class GEMM (denominator amplification ~1e5);
// R7 measured 138.7 TF (compiler emits v_pk_fma_f32) at only 24.7% occupancy
// -> grid-bound. R8: 64x64 tile / 128 threads / 8x4 per thread keeps R7's
// 32FMA:3read ratio and EXACT per-thread K-accumulation order (bit-identical
// output) while doubling the grid to 1536 blocks (6 blocks/CU, 12 waves/CU).
// Staging lane map: consecutive lanes -> consecutive LDS rows (2-way banks,
// free; R7 measured 0 conflicts with this pattern).
// ---------------------------------------------------------------------------
__global__ __launch_bounds__(128) void gemm1_f32(
    const float* __restrict__ A, const float* __restrict__ B,
    float* __restrict__ C) {
  __shared__ float As[32][68];   // [k][m]
  __shared__ float Bs[32][68];   // [k][n]
  const int tid = threadIdx.x;
  const int tx = tid & 15, ty = tid >> 4;     // ty 0..7
  const int bm = blockIdx.y * 64, bn = blockIdx.x * 64;
  const int row = tid & 63, c4base = tid >> 6;  // 0..1

  float acc[8][4] = {};

  for (int k0 = 0; k0 < 512; k0 += 32) {
#pragma unroll
    for (int p = 0; p < 4; ++p) {
      int c4 = c4base + 2 * p;
      float4 fa = *(const float4*)(A + (size_t)(bm + row) * 512 + k0 + c4 * 4);
      As[c4 * 4 + 0][row] = fa.x; As[c4 * 4 + 1][row] = fa.y;
      As[c4 * 4 + 2][row] = fa.z; As[c4 * 4 + 3][row] = fa.w;
      float4 fb = *(const float4*)(B + (size_t)(bn + row) * 512 + k0 + c4 * 4);
      Bs[c4 * 4 + 0][row] = fb.x; Bs[c4 * 4 + 1][row] = fb.y;
      Bs[c4 * 4 + 2][row] = fb.z; Bs[c4 * 4 + 3][row] = fb.w;
    }
    __syncthreads();
#pragma unroll
    for (int kk = 0; kk < 32; ++kk) {
      float a[8], b[4];
      *(float4*)&a[0] = *(const float4*)&As[kk][ty * 8];
      *(float4*)&a[4] = *(const float4*)&As[kk][ty * 8 + 4];
      *(float4*)&b[0] = *(const float4*)&Bs[kk][tx * 4];
#pragma unroll
      for (int i = 0; i < 8; ++i)
#pragma unroll
        for (int j = 0; j < 4; ++j) acc[i][j] += a[i] * b[j];
    }
    __syncthreads();
  }

#pragma unroll
  for (int i = 0; i < 8; ++i) {
    size_t r = bm + ty * 8 + i;
    float4 v;
    v.x = acc[i][0]; v.y = acc[i][1]; v.z = acc[i][2]; v.w = acc[i][3];
    *(float4*)(C + r * (size_t)TQKV + bn + tx * 4) = v;
  }
}

// ---------------------------------------------------------------------------
// 2-way split fp32 -> (hi, lo*2^11) for GEMM2 operands (validated R4/R7:
// GEMM2's split error is subdominant — absmax bit-equal to all-fp32).
// ---------------------------------------------------------------------------
__global__ __launch_bounds__(256) void split_f16_k(
    const float* __restrict__ s, _Float16* __restrict__ hi,
    _Float16* __restrict__ lo, int n4) {
  int i = blockIdx.x * 256 + threadIdx.x;
  if (i >= n4) return;
  float4 a = ((const float4*)s)[i];
  half4 h, l;
  float av[4] = {a.x, a.y, a.z, a.w};
#pragma unroll
  for (int j = 0; j < 4; ++j) {
    _Float16 hh = (_Float16)av[j];
    h[j] = hh;
    l[j] = (_Float16)((av[j] - (float)hh) * 2048.0f);
  }
  ((half4*)hi)[i] = h;
  ((half4*)lo)[i] = l;
}

// ---------------------------------------------------------------------------
// 2-term split-f16 NT GEMM via MFMA (GEMM2 ONLY — R4-exact, proven passing).
// ---------------------------------------------------------------------------
__global__ __launch_bounds__(256) void gemm_split_nt(
    const _Float16* __restrict__ Ah, const _Float16* __restrict__ Al,
    const _Float16* __restrict__ Bh, const _Float16* __restrict__ Bl,
    const float* __restrict__ bias, float* __restrict__ C,
    int Ndim, int Kd) {
  constexpr int BM = 128, BN = 64, BK = 32;
  __shared__ _Float16 lds[(2 * BM + 2 * BN) * BK];  // 24 KB
  constexpr int AHo = 0;
  constexpr int ALo = BM * BK;
  constexpr int BHo = 2 * BM * BK;
  constexpr int BLo = 2 * BM * BK + BN * BK;

  const int tid = threadIdx.x;
  const int wave = tid >> 6, lane = tid & 63;
  const int lq = lane >> 4, lm = lane & 15;
  const int bm = blockIdx.y * BM, bn = blockIdx.x * BN;

  f32x4 acc[2][4] = {};
  f32x4 corr[2][4] = {};

  const int nsteps = Kd >> 5;
  for (int ks = 0; ks < nsteps; ++ks) {
    const int k0 = ks * BK;
    for (int idx = wave; idx < 24; idx += 4) {
      int t, j;
      if (idx < 8)       { t = 0; j = idx; }
      else if (idx < 16) { t = 1; j = idx - 8; }
      else if (idx < 20) { t = 2; j = idx - 16; }
      else               { t = 3; j = idx - 20; }
      const int row = j * 16 + (lane >> 2);
      const _Float16* g;
      _Float16* l;
      if (t == 0)      { g = Ah + (size_t)(bm + row) * Kd; l = lds + AHo + j * 16 * BK; }
      else if (t == 1) { g = Al + (size_t)(bm + row) * Kd; l = lds + ALo + j * 16 * BK; }
      else if (t == 2) { g = Bh + (size_t)(bn + row) * Kd; l = lds + BHo + j * 16 * BK; }
      else             { g = Bl + (size_t)(bn + row) * Kd; l = lds + BLo + j * 16 * BK; }
      g += k0 + (lane & 3) * 8;
      __builtin_amdgcn_global_load_lds(AS1(g), AS3(l), 16, 0, 0);
    }
    __syncthreads();

    half8 ahf[2], alf[2], bhf[4], blf[4];
    const int mwo = wave * 32;
#pragma unroll
    for (int fi = 0; fi < 2; ++fi) {
      ahf[fi] = *(const half8*)&lds[AHo + (mwo + fi * 16 + lm) * BK + lq * 8];
      alf[fi] = *(const half8*)&lds[ALo + (mwo + fi * 16 + lm) * BK + lq * 8];
    }
#pragma unroll
    for (int fj = 0; fj < 4; ++fj) {
      bhf[fj] = *(const half8*)&lds[BHo + (fj * 16 + lm) * BK + lq * 8];
      blf[fj] = *(const half8*)&lds[BLo + (fj * 16 + lm) * BK + lq * 8];
    }
#pragma unroll
    for (int fi = 0; fi < 2; ++fi)
#pragma unroll
      for (int fj = 0; fj < 4; ++fj) {
        acc[fi][fj] = __builtin_amdgcn_mfma_f32_16x16x32_f16(
            ahf[fi], bhf[fj], acc[fi][fj], 0, 0, 0);
        corr[fi][fj] = __builtin_amdgcn_mfma_f32_16x16x32_f16(
            ahf[fi], blf[fj], corr[fi][fj], 0, 0, 0);
        corr[fi][fj] = __builtin_amdgcn_mfma_f32_16x16x32_f16(
            alf[fi], bhf[fj], corr[fi][fj], 0, 0, 0);
      }
    __syncthreads();
  }

  // Epilogue: C/D layout col = lane&15, row = quad*4 + reg
#pragma unroll
  for (int fi = 0; fi < 2; ++fi) {
    const int m0 = bm + wave * 32 + fi * 16 + lq * 4;
#pragma unroll
    for (int fj = 0; fj < 4; ++fj) {
      const int n = bn + fj * 16 + lm;
      const float bb = bias ? bias[n] : 0.f;
      f32x4 v = acc[fi][fj];
      f32x4 cv = corr[fi][fj];
#pragma unroll
      for (int r = 0; r < 4; ++r)
        C[(size_t)(m0 + r) * Ndim + n] = v[r] + cv[r] * (1.0f / 2048.0f) + bb;
    }
  }
}

// ---------------------------------------------------------------------------
// Pass 1 (FUSED LN): per (b,h,chunk) block:
//  a) load raw K,V head-tiles to LDS
//  b) per-row LayerNorm in LDS (torch semantics: biased var, eps inside sqrt)
//  c) write normalized k,v back to qkv (chunk_attn reads them later)
//  d) S_c = K^T V and kc_c = colsum(K) -> cbuf
// Replaces the separate ln_kv dispatch (saves a launch + 66 MB traffic).
// ---------------------------------------------------------------------------
__global__ __launch_bounds__(256) void chunk_sums_ln(
    float* __restrict__ qkv, const float* __restrict__ lnk_w,
    const float* __restrict__ lnk_b, const float* __restrict__ lnv_w,
    const float* __restrict__ lnv_b, float* __restrict__ cbuf) {
  int blk = blockIdx.x;
  int c = blk % NCH;
  int bh = blk / NCH;
  int h = bh % Hh, b = bh / Hh;
  __shared__ float Ks[CH][68];
  __shared__ float Vs[CH][68];
  int tid = threadIdx.x;
  float* base = qkv + (size_t)(b * Nn + c * CH) * TQKV + h * Dd;
  for (int i = tid; i < CH * 16; i += 256) {
    int row = i >> 4, c4 = i & 15;
    *(float4*)&Ks[row][c4 * 4] =
        *(const float4*)(base + (size_t)row * TQKV + INNER + c4 * 4);
    *(float4*)&Vs[row][c4 * 4] =
        *(const float4*)(base + (size_t)row * TQKV + 2 * INNER + c4 * 4);
  }
  __syncthreads();

  // LayerNorm: thread t<64 -> K row t; 64<=t<128 -> V row t-64.
  if (tid < 128) {
    bool isv = tid >= 64;
    int row = tid & 63;
    float* R = isv ? &Vs[row][0] : &Ks[row][0];
    float s = 0.f, s2 = 0.f;
#pragma unroll
    for (int j = 0; j < 64; j += 4) {
      float4 v = *(const float4*)&R[j];
      s += v.x + v.y + v.z + v.w;
      s2 += v.x * v.x + v.y * v.y + v.z * v.z + v.w * v.w;
    }
    float mean = s * (1.f / 64.f);
    float var = s2 * (1.f / 64.f) - mean * mean;
    float inv = 1.0f / sqrtf(var + EPSF);
    const float* w = isv ? lnv_w : lnk_w;
    const float* bb = isv ? lnv_b : lnk_b;
#pragma unroll
    for (int j = 0; j < 64; ++j)
      R[j] = (R[j] - mean) * inv * w[h * Dd + j] + bb[h * Dd + j];
  }
  __syncthreads();

  // Write normalized k,v back (coalesced)
  for (int i = tid; i < CH * 16; i += 256) {
    int row = i >> 4, c4 = i & 15;
    *(float4*)(base + (size_t)row * TQKV + INNER + c4 * 4) =
        *(const float4*)&Ks[row][c4 * 4];
    *(float4*)(base + (size_t)row * TQKV + 2 * INNER + c4 * 4) =
        *(const float4*)&Vs[row][c4 * 4];
  }

  // S = K^T V, kc = colsum(K)
  int d0 = (tid >> 4) * 4, e0 = (tid & 15) * 4;
  float acc[4][4] = {};
  float kc[4] = {0.f, 0.f, 0.f, 0.f};
  for (int n = 0; n < CH; ++n) {
    float4 kv = *(const float4*)&Ks[n][d0];
    float4 vv = *(const float4*)&Vs[n][e0];
    float ka[4] = {kv.x, kv.y, kv.z, kv.w};
    float va[4] = {vv.x, vv.y, vv.z, vv.w};
#pragma unroll
    for (int i = 0; i < 4; ++i)
#pragma unroll
      for (int j = 0; j < 4; ++j) acc[i][j] += ka[i] * va[j];
    if (e0 == 0) {
#pragma unroll
      for (int i = 0; i < 4; ++i) kc[i] += ka[i];
    }
  }
  float* out = cbuf + (size_t)blk * CSZ;
#pragma unroll
  for (int i = 0; i < 4; ++i) {
    float4 r;
    r.x = acc[i][0]; r.y = acc[i][1]; r.z = acc[i][2]; r.w = acc[i][3];
    *(float4*)(out + (size_t)(d0 + i) * Dd + e0) = r;
  }
  if (e0 == 0) {
#pragma unroll
    for (int i = 0; i < 4; ++i) out[Dd * Dd + d0 + i] = kc[i];
  }
}

// ---------------------------------------------------------------------------
// Pass 2: exclusive prefix over chunks, parallel over columns.
// ---------------------------------------------------------------------------
__global__ __launch_bounds__(256) void chunk_prefix(float* __restrict__ cbuf) {
  int bh = blockIdx.y;
  int i = blockIdx.x * 256 + threadIdx.x;
  if (i >= CSZ) return;
  float* p = cbuf + (size_t)bh * NCH * CSZ + i;
  float carry = 0.f;
  for (int c = 0; c < NCH; ++c) {
    float t = p[(size_t)c * CSZ];
    p[(size_t)c * CSZ] = carry;
    carry += t;
  }
}

// ---------------------------------------------------------------------------
// Pass 3: per chunk attention; writes attn split to f16 hi/lo for GEMM2.
// LDS cut 92->74.5 KB: Ps overlays Ks (extra barrier isolates the phases)
// -> 2 blocks/CU on this latency-bound kernel (was 1).
// ---------------------------------------------------------------------------
__global__ __launch_bounds__(256) void chunk_attn(
    const float* __restrict__ qkv, const float* __restrict__ cbuf,
    _Float16* __restrict__ atth, _Float16* __restrict__ attl) {
  int blk = blockIdx.x;
  int c = blk % NCH;
  int bh = blk / NCH;
  int h = bh % Hh, b = bh / Hh;
  __shared__ float Qs[64][68];   // [d][n] transposed
  __shared__ float Ks[64][68];   // [d][m] transposed; later reused as Ps[m][n]
  __shared__ float Vs[64][68];   // [m][e]
  __shared__ float Ss[64][68];   // [d][e] S_prefix
  __shared__ float kcs[64];
  __shared__ float rs[64][17];
  __shared__ float denomS[64];
  float (*Ps)[68] = Ks;          // overlay

  int tid = threadIdx.x;
  int tx = tid & 15, ty = tid >> 4;
  const float* base = qkv + (size_t)(b * Nn + c * CH) * TQKV + h * Dd;
  for (int i = tid; i < CH * 16; i += 256) {
    int row = i >> 4, c4 = i & 15;
    float4 fq = *(const float4*)(base + (size_t)row * TQKV + c4 * 4);
    Qs[c4 * 4 + 0][row] = fq.x; Qs[c4 * 4 + 1][row] = fq.y;
    Qs[c4 * 4 + 2][row] = fq.z; Qs[c4 * 4 + 3][row] = fq.w;
    float4 fk = *(const float4*)(base + (size_t)row * TQKV + INNER + c4 * 4);
    Ks[c4 * 4 + 0][row] = fk.x; Ks[c4 * 4 + 1][row] = fk.y;
    Ks[c4 * 4 + 2][row] = fk.z; Ks[c4 * 4 + 3][row] = fk.w;
    float4 fv = *(const float4*)(base + (size_t)row * TQKV + 2 * INNER + c4 * 4);
    *(float4*)&Vs[row][c4 * 4] = fv;
  }
  const float* sp = cbuf + (size_t)blk * CSZ;
  for (int i = tid; i < 1024; i += 256) {
    int row = i >> 4;
    *(float4*)&Ss[row][(i & 15) * 4] = *(const float4*)(sp + (size_t)i * 4);
  }
  if (tid < 16) {
    float4 f = *(const float4*)(sp + Dd * Dd + tid * 4);
    kcs[tid * 4 + 0] = f.x; kcs[tid * 4 + 1] = f.y;
    kcs[tid * 4 + 2] = f.z; kcs[tid * 4 + 3] = f.w;
  }
  __syncthreads();

  // P = Q K^T into registers
  float accP[4][4] = {};
  for (int kk = 0; kk < 64; ++kk) {
    float4 qa = *(const float4*)&Qs[kk][ty * 4];
    float4 kb = *(const float4*)&Ks[kk][tx * 4];
    float qv[4] = {qa.x, qa.y, qa.z, qa.w};
    float kv[4] = {kb.x, kb.y, kb.z, kb.w};
#pragma unroll
    for (int i = 0; i < 4; ++i)
#pragma unroll
      for (int j = 0; j < 4; ++j) accP[i][j] += qv[i] * kv[j];
  }
  __syncthreads();  // all Ks reads done before Ps (same memory) is written

  // mask + store Ps (overlaying Ks) + rowsum
#pragma unroll
  for (int i = 0; i < 4; ++i) {
    int n = ty * 4 + i;
    float rsum = 0.f;
#pragma unroll
    for (int j = 0; j < 4; ++j) {
      int m = tx * 4 + j;
      float p = (m <= n) ? accP[i][j] : 0.f;
      Ps[m][n] = p;
      rsum += p;
    }
    rs[n][tx] = rsum;
  }
  __syncthreads();

  // O = Q * S_prefix; denom
  float accO[4][4] = {};
  for (int d = 0; d < 64; ++d) {
    float4 qa = *(const float4*)&Qs[d][ty * 4];
    float4 sb = *(const float4*)&Ss[d][tx * 4];
    float qv[4] = {qa.x, qa.y, qa.z, qa.w};
    float sv[4] = {sb.x, sb.y, sb.z, sb.w};
#pragma unroll
    for (int i = 0; i < 4; ++i)
#pragma unroll
      for (int j = 0; j < 4; ++j) accO[i][j] += qv[i] * sv[j];
  }
  if (tid < 64) {
    int n = tid;
    float qkc = 0.f, qs = 0.f;
    for (int d = 0; d < 64; ++d) {
      float q = Qs[d][n];
      qkc += q * kcs[d];
      qs += q;
    }
    float rsum = 0.f;
#pragma unroll
    for (int t2 = 0; t2 < 16; ++t2) rsum += rs[n][t2];
    denomS[n] = qkc + rsum + EPSF * qs;
  }
  __syncthreads();

  // O += P_masked * V
  for (int m = 0; m < 64; ++m) {
    float4 pa = *(const float4*)&Ps[m][ty * 4];
    float4 vb = *(const float4*)&Vs[m][tx * 4];
    float pv[4] = {pa.x, pa.y, pa.z, pa.w};
    float vv[4] = {vb.x, vb.y, vb.z, vb.w};
#pragma unroll
    for (int i = 0; i < 4; ++i)
#pragma unroll
      for (int j = 0; j < 4; ++j) accO[i][j] += pv[i] * vv[j];
  }

  size_t obase = (size_t)(b * Nn + c * CH) * INNER + h * Dd;
#pragma unroll
  for (int i = 0; i < 4; ++i) {
    int n = ty * 4 + i;
    float dinv = 1.0f / denomS[n];
    float scale = dinv * (1.0f / (float)Nn);
    half4 hv, lv;
#pragma unroll
    for (int j = 0; j < 4; ++j) {
      float o = accO[i][j] * scale;
      _Float16 hh = (_Float16)o;
      hv[j] = hh;
      lv[j] = (_Float16)((o - (float)hh) * 2048.0f);
    }
    *(half4*)(atth + obase + (size_t)n * INNER + tx * 4) = hv;
    *(half4*)(attl + obase + (size_t)n * INNER + tx * 4) = lv;
  }
}

// ---------------------------------------------------------------------------
extern "C" void kernel_launch(void* const* d_in, const int* in_sizes, int n_in,
                              void* d_out, int out_size, void* d_ws,
                              size_t ws_size, hipStream_t stream) {
  const float* x     = (const float*)d_in[0];
  const float* w_qkv = (const float*)d_in[1];
  const float* lnk_w = (const float*)d_in[2];
  const float* lnk_b = (const float*)d_in[3];
  const float* lnv_w = (const float*)d_in[4];
  const float* lnv_b = (const float*)d_in[5];
  const float* w_out = (const float*)d_in[6];
  const float* b_out = (const float*)d_in[7];
  float* out = (float*)d_out;

  // Workspace layout (~43 MB):
  float* qkv  = (float*)d_ws;                      // 4096*1536 fp32
  float* cbuf = qkv + (size_t)Mm * TQKV;           // 512*4160 fp32
  _Float16* atth = (_Float16*)(cbuf + (size_t)Bb * Hh * NCH * CSZ);
  _Float16* attl = atth + (size_t)Mm * INNER;
  _Float16* woh  = attl + (size_t)Mm * INNER;
  _Float16* wol  = woh + (size_t)INNER * 512;

  // 1. QKV GEMM (fp32 pk-fma; 64x64 tile, 1536 blocks = 6/CU)
  gemm1_f32<<<dim3(TQKV / 64, Mm / 64), 128, 0, stream>>>(x, w_qkv, qkv);

  // 2. Fused LN(k,v) + per-chunk K^T V + colsum(K)
  chunk_sums_ln<<<Bb * Hh * NCH, 256, 0, stream>>>(
      qkv, lnk_w, lnk_b, lnv_w, lnv_b, cbuf);

  // 3. Exclusive prefix over chunks (parallel over columns)
  chunk_prefix<<<dim3((CSZ + 255) / 256, Bb * Hh), 256, 0, stream>>>(cbuf);

  // 4. Split w_out for GEMM2
  split_f16_k<<<256, 256, 0, stream>>>(w_out, woh, wol, INNER * 512 / 4);

  // 5. Per-chunk attention -> attn split f16 (74.5 KB LDS, 2 blocks/CU)
  chunk_attn<<<Bb * Hh * NCH, 256, 0, stream>>>(qkv, cbuf, atth, attl);

  // 6. Output GEMM: out = attn * w_out^T + b_out (R4-exact split MFMA)
  gemm_split_nt<<<dim3(INNER / 64, Mm / 128), 256, 0, stream>>>(
      atth, attl, woh, wol, b_out, out, INNER, 512);
}

// Round 9
// 234.524 us; speedup vs baseline: 1.0156x; 1.0156x over previous
//
#include <hip/hip_runtime.h>

// Problem constants
constexpr int Bb   = 2;
constexpr int Nn   = 2048;
constexpr int Hh   = 8;
constexpr int Dd   = 64;
constexpr int Mm   = Bb * Nn;      // 4096 rows
constexpr int TQKV = 1536;         // 3 * H * D
constexpr int INNER = Hh * Dd;     // 512
constexpr int CH   = 64;           // chunk length
constexpr int NCH  = Nn / CH;      // 32 chunks per (b,h)
constexpr int CSZ  = Dd * Dd + Dd; // 4160 floats per chunk record (S + kc)
constexpr float EPSF = 1e-7f;

typedef _Float16 half8 __attribute__((ext_vector_type(8)));
typedef _Float16 half4 __attribute__((ext_vector_type(4)));
typedef float f32x4 __attribute__((ext_vector_type(4)));

#define AS1(p) ((const __attribute__((address_space(1))) unsigned int*)(p))
#define AS3(p) ((__attribute__((address_space(3))) unsigned int*)(p))

// ---------------------------------------------------------------------------
// GEMM1-qk (fp32 VALU, pk-fma): qkv[:, 0:1024] = x * w_qkv[0:1024]^T.
// R7-exact config (93 µs / 138.7 TF = 88% of fp32 peak at full N):
// 128x64 tile, 256 threads, 8x4/thread, BK=32, conflict-free staging.
// R9: N shrunk to 1024 (q,k only) — v carved out to the split-MFMA path,
// which R2/R3 (bit-identical absmax with v at plain f16) and R4/R7
// (split subdominant on spike-magnitude values) validate as safe.
// ---------------------------------------------------------------------------
__global__ __launch_bounds__(256) void gemm1_f32(
    const float* __restrict__ A, const float* __restrict__ B,
    float* __restrict__ C) {
  __shared__ float As[32][132];  // [k][m]
  __shared__ float Bs[32][68];   // [k][n]
  const int tid = threadIdx.x;
  const int tx = tid & 15, ty = tid >> 4;
  const int bm = blockIdx.y * 128, bn = blockIdx.x * 64;
  const int rowA = tid & 127, c4a = tid >> 7;  // 0..1
  const int rowB = tid & 63,  c4b = tid >> 6;  // 0..3

  float acc[8][4] = {};

  for (int k0 = 0; k0 < 512; k0 += 32) {
#pragma unroll
    for (int p = 0; p < 4; ++p) {
      int c4 = c4a + 2 * p;
      float4 fa = *(const float4*)(A + (size_t)(bm + rowA) * 512 + k0 + c4 * 4);
      As[c4 * 4 + 0][rowA] = fa.x; As[c4 * 4 + 1][rowA] = fa.y;
      As[c4 * 4 + 2][rowA] = fa.z; As[c4 * 4 + 3][rowA] = fa.w;
    }
#pragma unroll
    for (int p = 0; p < 2; ++p) {
      int c4 = c4b + 4 * p;
      float4 fb = *(const float4*)(B + (size_t)(bn + rowB) * 512 + k0 + c4 * 4);
      Bs[c4 * 4 + 0][rowB] = fb.x; Bs[c4 * 4 + 1][rowB] = fb.y;
      Bs[c4 * 4 + 2][rowB] = fb.z; Bs[c4 * 4 + 3][rowB] = fb.w;
    }
    __syncthreads();
#pragma unroll
    for (int kk = 0; kk < 32; ++kk) {
      float a[8], b[4];
      *(float4*)&a[0] = *(const float4*)&As[kk][ty * 8];
      *(float4*)&a[4] = *(const float4*)&As[kk][ty * 8 + 4];
      *(float4*)&b[0] = *(const float4*)&Bs[kk][tx * 4];
#pragma unroll
      for (int i = 0; i < 8; ++i)
#pragma unroll
        for (int j = 0; j < 4; ++j) acc[i][j] += a[i] * b[j];
    }
    __syncthreads();
  }

#pragma unroll
  for (int i = 0; i < 8; ++i) {
    size_t row = bm + ty * 8 + i;
    float4 r;
    r.x = acc[i][0]; r.y = acc[i][1]; r.z = acc[i][2]; r.w = acc[i][3];
    *(float4*)(C + row * (size_t)TQKV + bn + tx * 4) = r;
  }
}

// ---------------------------------------------------------------------------
// 2-way split fp32 -> (hi, lo*2^11).
// ---------------------------------------------------------------------------
__global__ __launch_bounds__(256) void split_f16_k(
    const float* __restrict__ s, _Float16* __restrict__ hi,
    _Float16* __restrict__ lo, int n4) {
  int i = blockIdx.x * 256 + threadIdx.x;
  if (i >= n4) return;
  float4 a = ((const float4*)s)[i];
  half4 h, l;
  float av[4] = {a.x, a.y, a.z, a.w};
#pragma unroll
  for (int j = 0; j < 4; ++j) {
    _Float16 hh = (_Float16)av[j];
    h[j] = hh;
    l[j] = (_Float16)((av[j] - (float)hh) * 2048.0f);
  }
  ((half4*)hi)[i] = h;
  ((half4*)lo)[i] = l;
}

// ---------------------------------------------------------------------------
// 2-term split-f16 NT GEMM via MFMA (R4-exact numerics, proven passing).
// Used for: v-columns of GEMM1 (C points at qkv+1024, Ndim=TQKV) and GEMM2.
// ---------------------------------------------------------------------------
__global__ __launch_bounds__(256) void gemm_split_nt(
    const _Float16* __restrict__ Ah, const _Float16* __restrict__ Al,
    const _Float16* __restrict__ Bh, const _Float16* __restrict__ Bl,
    const float* __restrict__ bias, float* __restrict__ C,
    int Ndim, int Kd) {
  constexpr int BM = 128, BN = 64, BK = 32;
  __shared__ _Float16 lds[(2 * BM + 2 * BN) * BK];  // 24 KB
  constexpr int AHo = 0;
  constexpr int ALo = BM * BK;
  constexpr int BHo = 2 * BM * BK;
  constexpr int BLo = 2 * BM * BK + BN * BK;

  const int tid = threadIdx.x;
  const int wave = tid >> 6, lane = tid & 63;
  const int lq = lane >> 4, lm = lane & 15;
  const int bm = blockIdx.y * BM, bn = blockIdx.x * BN;

  f32x4 acc[2][4] = {};
  f32x4 corr[2][4] = {};

  const int nsteps = Kd >> 5;
  for (int ks = 0; ks < nsteps; ++ks) {
    const int k0 = ks * BK;
    for (int idx = wave; idx < 24; idx += 4) {
      int t, j;
      if (idx < 8)       { t = 0; j = idx; }
      else if (idx < 16) { t = 1; j = idx - 8; }
      else if (idx < 20) { t = 2; j = idx - 16; }
      else               { t = 3; j = idx - 20; }
      const int row = j * 16 + (lane >> 2);
      const _Float16* g;
      _Float16* l;
      if (t == 0)      { g = Ah + (size_t)(bm + row) * Kd; l = lds + AHo + j * 16 * BK; }
      else if (t == 1) { g = Al + (size_t)(bm + row) * Kd; l = lds + ALo + j * 16 * BK; }
      else if (t == 2) { g = Bh + (size_t)(bn + row) * Kd; l = lds + BHo + j * 16 * BK; }
      else             { g = Bl + (size_t)(bn + row) * Kd; l = lds + BLo + j * 16 * BK; }
      g += k0 + (lane & 3) * 8;
      __builtin_amdgcn_global_load_lds(AS1(g), AS3(l), 16, 0, 0);
    }
    __syncthreads();

    half8 ahf[2], alf[2], bhf[4], blf[4];
    const int mwo = wave * 32;
#pragma unroll
    for (int fi = 0; fi < 2; ++fi) {
      ahf[fi] = *(const half8*)&lds[AHo + (mwo + fi * 16 + lm) * BK + lq * 8];
      alf[fi] = *(const half8*)&lds[ALo + (mwo + fi * 16 + lm) * BK + lq * 8];
    }
#pragma unroll
    for (int fj = 0; fj < 4; ++fj) {
      bhf[fj] = *(const half8*)&lds[BHo + (fj * 16 + lm) * BK + lq * 8];
      blf[fj] = *(const half8*)&lds[BLo + (fj * 16 + lm) * BK + lq * 8];
    }
#pragma unroll
    for (int fi = 0; fi < 2; ++fi)
#pragma unroll
      for (int fj = 0; fj < 4; ++fj) {
        acc[fi][fj] = __builtin_amdgcn_mfma_f32_16x16x32_f16(
            ahf[fi], bhf[fj], acc[fi][fj], 0, 0, 0);
        corr[fi][fj] = __builtin_amdgcn_mfma_f32_16x16x32_f16(
            ahf[fi], blf[fj], corr[fi][fj], 0, 0, 0);
        corr[fi][fj] = __builtin_amdgcn_mfma_f32_16x16x32_f16(
            alf[fi], bhf[fj], corr[fi][fj], 0, 0, 0);
      }
    __syncthreads();
  }

  // Epilogue: C/D layout col = lane&15, row = quad*4 + reg
#pragma unroll
  for (int fi = 0; fi < 2; ++fi) {
    const int m0 = bm + wave * 32 + fi * 16 + lq * 4;
#pragma unroll
    for (int fj = 0; fj < 4; ++fj) {
      const int n = bn + fj * 16 + lm;
      const float bb = bias ? bias[n] : 0.f;
      f32x4 v = acc[fi][fj];
      f32x4 cv = corr[fi][fj];
#pragma unroll
      for (int r = 0; r < 4; ++r)
        C[(size_t)(m0 + r) * Ndim + n] = v[r] + cv[r] * (1.0f / 2048.0f) + bb;
    }
  }
}

// ---------------------------------------------------------------------------
// Pass 1 (FUSED LN): LN(k,v) in LDS + writeback + S_c = K^T V + colsum(K).
// (R8-validated: saved ~11 µs vs separate ln_kv dispatch.)
// ---------------------------------------------------------------------------
__global__ __launch_bounds__(256) void chunk_sums_ln(
    float* __restrict__ qkv, const float* __restrict__ lnk_w,
    const float* __restrict__ lnk_b, const float* __restrict__ lnv_w,
    const float* __restrict__ lnv_b, float* __restrict__ cbuf) {
  int blk = blockIdx.x;
  int c = blk % NCH;
  int bh = blk / NCH;
  int h = bh % Hh, b = bh / Hh;
  __shared__ float Ks[CH][68];
  __shared__ float Vs[CH][68];
  int tid = threadIdx.x;
  float* base = qkv + (size_t)(b * Nn + c * CH) * TQKV + h * Dd;
  for (int i = tid; i < CH * 16; i += 256) {
    int row = i >> 4, c4 = i & 15;
    *(float4*)&Ks[row][c4 * 4] =
        *(const float4*)(base + (size_t)row * TQKV + INNER + c4 * 4);
    *(float4*)&Vs[row][c4 * 4] =
        *(const float4*)(base + (size_t)row * TQKV + 2 * INNER + c4 * 4);
  }
  __syncthreads();

  if (tid < 128) {
    bool isv = tid >= 64;
    int row = tid & 63;
    float* R = isv ? &Vs[row][0] : &Ks[row][0];
    float s = 0.f, s2 = 0.f;
#pragma unroll
    for (int j = 0; j < 64; j += 4) {
      float4 v = *(const float4*)&R[j];
      s += v.x + v.y + v.z + v.w;
      s2 += v.x * v.x + v.y * v.y + v.z * v.z + v.w * v.w;
    }
    float mean = s * (1.f / 64.f);
    float var = s2 * (1.f / 64.f) - mean * mean;
    float inv = 1.0f / sqrtf(var + EPSF);
    const float* w = isv ? lnv_w : lnk_w;
    const float* bb = isv ? lnv_b : lnk_b;
#pragma unroll
    for (int j = 0; j < 64; ++j)
      R[j] = (R[j] - mean) * inv * w[h * Dd + j] + bb[h * Dd + j];
  }
  __syncthreads();

  for (int i = tid; i < CH * 16; i += 256) {
    int row = i >> 4, c4 = i & 15;
    *(float4*)(base + (size_t)row * TQKV + INNER + c4 * 4) =
        *(const float4*)&Ks[row][c4 * 4];
    *(float4*)(base + (size_t)row * TQKV + 2 * INNER + c4 * 4) =
        *(const float4*)&Vs[row][c4 * 4];
  }

  int d0 = (tid >> 4) * 4, e0 = (tid & 15) * 4;
  float acc[4][4] = {};
  float kc[4] = {0.f, 0.f, 0.f, 0.f};
  for (int n = 0; n < CH; ++n) {
    float4 kv = *(const float4*)&Ks[n][d0];
    float4 vv = *(const float4*)&Vs[n][e0];
    float ka[4] = {kv.x, kv.y, kv.z, kv.w};
    float va[4] = {vv.x, vv.y, vv.z, vv.w};
#pragma unroll
    for (int i = 0; i < 4; ++i)
#pragma unroll
      for (int j = 0; j < 4; ++j) acc[i][j] += ka[i] * va[j];
    if (e0 == 0) {
#pragma unroll
      for (int i = 0; i < 4; ++i) kc[i] += ka[i];
    }
  }
  float* out = cbuf + (size_t)blk * CSZ;
#pragma unroll
  for (int i = 0; i < 4; ++i) {
    float4 r;
    r.x = acc[i][0]; r.y = acc[i][1]; r.z = acc[i][2]; r.w = acc[i][3];
    *(float4*)(out + (size_t)(d0 + i) * Dd + e0) = r;
  }
  if (e0 == 0) {
#pragma unroll
    for (int i = 0; i < 4; ++i) out[Dd * Dd + d0 + i] = kc[i];
  }
}

// ---------------------------------------------------------------------------
// Pass 2: exclusive prefix over chunks, parallel over columns.
// ---------------------------------------------------------------------------
__global__ __launch_bounds__(256) void chunk_prefix(float* __restrict__ cbuf) {
  int bh = blockIdx.y;
  int i = blockIdx.x * 256 + threadIdx.x;
  if (i >= CSZ) return;
  float* p = cbuf + (size_t)bh * NCH * CSZ + i;
  float carry = 0.f;
  for (int c = 0; c < NCH; ++c) {
    float t = p[(size_t)c * CSZ];
    p[(size_t)c * CSZ] = carry;
    carry += t;
  }
}

// ---------------------------------------------------------------------------
// Pass 3: per chunk attention; writes attn split to f16 hi/lo for GEMM2.
// Ps overlays Ks (74.5 KB LDS, 2 blocks/CU).
// ---------------------------------------------------------------------------
__global__ __launch_bounds__(256) void chunk_attn(
    const float* __restrict__ qkv, const float* __restrict__ cbuf,
    _Float16* __restrict__ atth, _Float16* __restrict__ attl) {
  int blk = blockIdx.x;
  int c = blk % NCH;
  int bh = blk / NCH;
  int h = bh % Hh, b = bh / Hh;
  __shared__ float Qs[64][68];   // [d][n]
  __shared__ float Ks[64][68];   // [d][m]; later reused as Ps[m][n]
  __shared__ float Vs[64][68];   // [m][e]
  __shared__ float Ss[64][68];   // [d][e]
  __shared__ float kcs[64];
  __shared__ float rs[64][17];
  __shared__ float denomS[64];
  float (*Ps)[68] = Ks;          // overlay

  int tid = threadIdx.x;
  int tx = tid & 15, ty = tid >> 4;
  const float* base = qkv + (size_t)(b * Nn + c * CH) * TQKV + h * Dd;
  for (int i = tid; i < CH * 16; i += 256) {
    int row = i >> 4, c4 = i & 15;
    float4 fq = *(const float4*)(base + (size_t)row * TQKV + c4 * 4);
    Qs[c4 * 4 + 0][row] = fq.x; Qs[c4 * 4 + 1][row] = fq.y;
    Qs[c4 * 4 + 2][row] = fq.z; Qs[c4 * 4 + 3][row] = fq.w;
    float4 fk = *(const float4*)(base + (size_t)row * TQKV + INNER + c4 * 4);
    Ks[c4 * 4 + 0][row] = fk.x; Ks[c4 * 4 + 1][row] = fk.y;
    Ks[c4 * 4 + 2][row] = fk.z; Ks[c4 * 4 + 3][row] = fk.w;
    float4 fv = *(const float4*)(base + (size_t)row * TQKV + 2 * INNER + c4 * 4);
    *(float4*)&Vs[row][c4 * 4] = fv;
  }
  const float* sp = cbuf + (size_t)blk * CSZ;
  for (int i = tid; i < 1024; i += 256) {
    int row = i >> 4;
    *(float4*)&Ss[row][(i & 15) * 4] = *(const float4*)(sp + (size_t)i * 4);
  }
  if (tid < 16) {
    float4 f = *(const float4*)(sp + Dd * Dd + tid * 4);
    kcs[tid * 4 + 0] = f.x; kcs[tid * 4 + 1] = f.y;
    kcs[tid * 4 + 2] = f.z; kcs[tid * 4 + 3] = f.w;
  }
  __syncthreads();

  // P = Q K^T into registers
  float accP[4][4] = {};
  for (int kk = 0; kk < 64; ++kk) {
    float4 qa = *(const float4*)&Qs[kk][ty * 4];
    float4 kb = *(const float4*)&Ks[kk][tx * 4];
    float qv[4] = {qa.x, qa.y, qa.z, qa.w};
    float kv[4] = {kb.x, kb.y, kb.z, kb.w};
#pragma unroll
    for (int i = 0; i < 4; ++i)
#pragma unroll
      for (int j = 0; j < 4; ++j) accP[i][j] += qv[i] * kv[j];
  }
  __syncthreads();  // Ks reads done before Ps overlay is written

#pragma unroll
  for (int i = 0; i < 4; ++i) {
    int n = ty * 4 + i;
    float rsum = 0.f;
#pragma unroll
    for (int j = 0; j < 4; ++j) {
      int m = tx * 4 + j;
      float p = (m <= n) ? accP[i][j] : 0.f;
      Ps[m][n] = p;
      rsum += p;
    }
    rs[n][tx] = rsum;
  }
  __syncthreads();

  // O = Q * S_prefix; denom
  float accO[4][4] = {};
  for (int d = 0; d < 64; ++d) {
    float4 qa = *(const float4*)&Qs[d][ty * 4];
    float4 sb = *(const float4*)&Ss[d][tx * 4];
    float qv[4] = {qa.x, qa.y, qa.z, qa.w};
    float sv[4] = {sb.x, sb.y, sb.z, sb.w};
#pragma unroll
    for (int i = 0; i < 4; ++i)
#pragma unroll
      for (int j = 0; j < 4; ++j) accO[i][j] += qv[i] * sv[j];
  }
  if (tid < 64) {
    int n = tid;
    float qkc = 0.f, qs = 0.f;
    for (int d = 0; d < 64; ++d) {
      float q = Qs[d][n];
      qkc += q * kcs[d];
      qs += q;
    }
    float rsum = 0.f;
#pragma unroll
    for (int t2 = 0; t2 < 16; ++t2) rsum += rs[n][t2];
    denomS[n] = qkc + rsum + EPSF * qs;
  }
  __syncthreads();

  // O += P_masked * V
  for (int m = 0; m < 64; ++m) {
    float4 pa = *(const float4*)&Ps[m][ty * 4];
    float4 vb = *(const float4*)&Vs[m][tx * 4];
    float pv[4] = {pa.x, pa.y, pa.z, pa.w};
    float vv[4] = {vb.x, vb.y, vb.z, vb.w};
#pragma unroll
    for (int i = 0; i < 4; ++i)
#pragma unroll
      for (int j = 0; j < 4; ++j) accO[i][j] += pv[i] * vv[j];
  }

  size_t obase = (size_t)(b * Nn + c * CH) * INNER + h * Dd;
#pragma unroll
  for (int i = 0; i < 4; ++i) {
    int n = ty * 4 + i;
    float dinv = 1.0f / denomS[n];
    float scale = dinv * (1.0f / (float)Nn);
    half4 hv, lv;
#pragma unroll
    for (int j = 0; j < 4; ++j) {
      float o = accO[i][j] * scale;
      _Float16 hh = (_Float16)o;
      hv[j] = hh;
      lv[j] = (_Float16)((o - (float)hh) * 2048.0f);
    }
    *(half4*)(atth + obase + (size_t)n * INNER + tx * 4) = hv;
    *(half4*)(attl + obase + (size_t)n * INNER + tx * 4) = lv;
  }
}

// ---------------------------------------------------------------------------
extern "C" void kernel_launch(void* const* d_in, const int* in_sizes, int n_in,
                              void* d_out, int out_size, void* d_ws,
                              size_t ws_size, hipStream_t stream) {
  const float* x     = (const float*)d_in[0];
  const float* w_qkv = (const float*)d_in[1];
  const float* lnk_w = (const float*)d_in[2];
  const float* lnk_b = (const float*)d_in[3];
  const float* lnv_w = (const float*)d_in[4];
  const float* lnv_b = (const float*)d_in[5];
  const float* w_out = (const float*)d_in[6];
  const float* b_out = (const float*)d_in[7];
  float* out = (float*)d_out;

  // Workspace layout (~52 MB):
  float* qkv  = (float*)d_ws;                      // 4096*1536 fp32
  float* cbuf = qkv + (size_t)Mm * TQKV;           // 512*4160 fp32
  _Float16* atth = (_Float16*)(cbuf + (size_t)Bb * Hh * NCH * CSZ);
  _Float16* attl = atth + (size_t)Mm * INNER;
  _Float16* woh  = attl + (size_t)Mm * INNER;
  _Float16* wol  = woh + (size_t)INNER * 512;
  _Float16* xh   = wol + (size_t)INNER * 512;      // x split 4096x512
  _Float16* xl   = xh + (size_t)Mm * 512;
  _Float16* wvh  = xl + (size_t)Mm * 512;          // w_qkv v-rows split 512x512
  _Float16* wvl  = wvh + (size_t)INNER * 512;

  // 1a. Split x and the v-rows of w_qkv (rows 1024..1535)
  split_f16_k<<<2048, 256, 0, stream>>>(x, xh, xl, Mm * 512 / 4);
  split_f16_k<<<256, 256, 0, stream>>>(
      w_qkv + (size_t)1024 * 512, wvh, wvl, INNER * 512 / 4);

  // 1b. GEMM1-qk (fp32, N=1024): q,k need fp32-class (denominator)
  gemm1_f32<<<dim3(1024 / 64, Mm / 128), 256, 0, stream>>>(x, w_qkv, qkv);

  // 1c. GEMM1-v (2-term split MFMA, N=512): writes qkv cols 1024..1535
  gemm_split_nt<<<dim3(512 / 64, Mm / 128), 256, 0, stream>>>(
      xh, xl, wvh, wvl, nullptr, qkv + 1024, TQKV, 512);

  // 2. Fused LN(k,v) + per-chunk K^T V + colsum(K)
  chunk_sums_ln<<<Bb * Hh * NCH, 256, 0, stream>>>(
      qkv, lnk_w, lnk_b, lnv_w, lnv_b, cbuf);

  // 3. Exclusive prefix over chunks (parallel over columns)
  chunk_prefix<<<dim3((CSZ + 255) / 256, Bb * Hh), 256, 0, stream>>>(cbuf);

  // 4. Split w_out for GEMM2
  split_f16_k<<<256, 256, 0, stream>>>(w_out, woh, wol, INNER * 512 / 4);

  // 5. Per-chunk attention -> attn split f16
  chunk_attn<<<Bb * Hh * NCH, 256, 0, stream>>>(qkv, cbuf, atth, attl);

  // 6. Output GEMM: out = attn * w_out^T + b_out (2-term split MFMA)
  gemm_split_nt<<<dim3(INNER / 64, Mm / 128), 256, 0, stream>>>(
      atth, attl, woh, wol, b_out, out, INNER, 512);
}